// Round 15
// baseline (435.166 us; speedup 1.0000x reference)
//
#include <hip/hip_runtime.h>
#include <hip/hip_bf16.h>
#include <math.h>

typedef __hip_bfloat16 bf16;
typedef unsigned short ushort_t;
typedef unsigned int uint_t;
typedef __attribute__((ext_vector_type(8))) short bf16x8;
typedef __attribute__((ext_vector_type(4))) float f32x4;

#define NBMAX 1024   // max buckets (N <= 262144 for fast path; also guarantees src < 2^24)
#define BSH 8        // 256 nodes per bucket
#define CH 2560      // edges per kb_fill chunk (5/thread at 512 threads; ~34KB LDS -> 4 blocks/CU)
#define NCMAX 2048   // max chunks - kb_scanA local array bound
#define CSRCAP 6144  // LDS staging capacity per half-bucket in kb_csr (64KB -> 2 blocks/CU)

// flags[0..15]: 1 if float-array slot is bf16, 0 if fp32.
//   slot 0:x | per layer L(0..2): 1+5L:w_up 2+5L:w_down 3+5L:w_bias 4+5L:ew_up 5+5L:ew_down
// flags[16]: 1 if edge_index is int64 (little-endian, values < 2^31), else int32.
__device__ __forceinline__ float ldf(const void* p, long i, int isbf) {
    return isbf ? __bfloat162float(((const bf16*)p)[i]) : ((const float*)p)[i];
}
// int64 path: single 8B load (int2) instead of stride-2 4B load.
__device__ __forceinline__ int lde(const int* ei, int half, long e, long E, int is64) {
    long idx = half ? (E + e) : e;
    if (is64) return ((const int2*)ei)[idx].x;
    return ei[idx];
}
__device__ __forceinline__ float u2f(ushort_t u) {
    union { unsigned int i; float f; } v; v.i = ((unsigned)u) << 16; return v.f;
}
__device__ __forceinline__ ushort_t f2u(float f) {
    bf16 h = __float2bfloat16(f);
    return *reinterpret_cast<ushort_t*>(&h);
}
__device__ __forceinline__ float lo2f(unsigned sp) {
    union { unsigned i; float f; } v; v.i = sp << 16; return v.f;
}
__device__ __forceinline__ float hi2f(unsigned sp) {
    union { unsigned i; float f; } v; v.i = sp & 0xffff0000u; return v.f;
}

// ---------------------------------------------------------------- dtype detection
struct DetectArgs {
    const void* p[16];
    long n[16];
    const int* ei;
    long E;
    int* flags;
};

__global__ void k_detect(DetectArgs a) {
    __shared__ int cnt;
    if (threadIdx.x == 0) cnt = 0;
    __syncthreads();
    int b = blockIdx.x;
    int bad = 0;
    if (b < 16) {
        const bf16* p = (const bf16*)a.p[b];
        long m = a.n[b] < 4096 ? a.n[b] : 4096;
        for (long i = threadIdx.x; i < m; i += 256) {
            float v = __bfloat162float(p[i]);
            if (!(fabsf(v) < 100.0f)) bad++;
        }
        atomicAdd(&cnt, bad);
        __syncthreads();
        if (threadIdx.x == 0) a.flags[b] = ((long)cnt * 16 < m) ? 1 : 0;
    } else {
        long m = a.E / 2 < 4096 ? a.E / 2 : 4096;
        for (long i = threadIdx.x; i < m; i += 256) {
            if (a.ei[2 * i + 1] != 0) bad++;
        }
        atomicAdd(&cnt, bad);
        __syncthreads();
        if (threadIdx.x == 0) a.flags[16] = (cnt < (int)(m / 16) + 1) ? 1 : 0;
    }
}

// ================================================================ bucketed CSR build
// dir 0: dst=col (up-list), dir 1: dst=row (down-list). bucket = dst>>8.
// Weights RIDE THE SORT. Chunk write bases are DETERMINISTIC: kb_count writes
// per-chunk histograms hc[dir][chunk][b]; kb_scanA scans them across chunks;
// kb_fill reads its base directly -> zero global atomics, no RTT dependency.

// Both directions per chunk, one edge-read pass; coalesced histogram store.
__global__ void kb_count(const int* __restrict__ ei, long E, const int* __restrict__ flags,
                         int NB, int NC, int* __restrict__ hc) {
    __shared__ int h0[NBMAX], h1[NBMAX];
    for (int i = threadIdx.x; i < NB; i += 256) { h0[i] = 0; h1[i] = 0; }
    __syncthreads();
    int is64 = flags[16];
    int c = blockIdx.x;
    long base = (long)c * CH;
#pragma unroll
    for (int i = 0; i < CH / 256; i++) {
        long e = base + i * 256 + threadIdx.x;
        if (e < E) {
            int cc = lde(ei, 1, e, E, is64);   // dir0 dst=col
            int rr = lde(ei, 0, e, E, is64);   // dir1 dst=row
            atomicAdd(&h0[cc >> BSH], 1);
            atomicAdd(&h1[rr >> BSH], 1);
        }
    }
    __syncthreads();
    for (int b = threadIdx.x; b < NB; b += 256) {
        hc[((long)0 * NC + c) * NB + b] = h0[b];
        hc[((long)1 * NC + c) * NB + b] = h1[b];
    }
}

// Per-(bucket,dir): exclusive scan of hc over chunks (in place) + total -> bc.
__global__ void kb_scanA(int* __restrict__ hc, int NC, int NB, int* __restrict__ bc) {
    __shared__ int ssum[256];
    int b = blockIdx.x, d = blockIdx.y;
    int tid = threadIdx.x;
    int k = (NC + 255) / 256;          // <= 8 (NC <= NCMAX)
    int c0 = tid * k;
    int local[8];
    int s = 0;
    for (int i = 0; i < k; i++) {
        int c = c0 + i;
        int v = (c < NC) ? hc[((long)d * NC + c) * NB + b] : 0;
        local[i] = s; s += v;
    }
    ssum[tid] = s;
    __syncthreads();
    for (int dd = 1; dd < 256; dd <<= 1) {
        int t = (tid >= dd) ? ssum[tid - dd] : 0;
        __syncthreads();
        ssum[tid] += t;
        __syncthreads();
    }
    int base = ssum[tid] - s;
    for (int i = 0; i < k; i++) {
        int c = c0 + i;
        if (c < NC) hc[((long)d * NC + c) * NB + b] = base + local[i];
    }
    if (tid == 255) bc[d * NBMAX + b] = ssum[255];
}

// Bucket bases from totals (serial over NB per dir - tiny).
__global__ void kb_scanB(const int* __restrict__ bc, int* __restrict__ bb, int NB) {
    if (threadIdx.x < 2) {
        int dir = threadIdx.x;
        int acc = 0;
        for (int i = 0; i < NB; i++) { bb[dir * (NBMAX + 1) + i] = acc; acc += bc[dir * NBMAX + i]; }
        bb[dir * (NBMAX + 1) + NB] = acc;
    }
}

// Per-block counting-sort of a CH-edge chunk by bucket, bucket-contiguous
// global append at deterministic base bb[b]+hc[dir][chunk][b].
// Record: (src|local<<24, w1|w2<<16) int2 + w3 ushort.
// Also FUSES the mean outputs: dir 0 writes mu[e], dir 1 writes md[e].
__global__ __launch_bounds__(512) void kb_fill(
                        const int* __restrict__ ei, long E, const int* __restrict__ flags,
                        int NB, int NBp, int NC,
                        const int* __restrict__ hc, const int* __restrict__ bb,
                        const void* __restrict__ eu1, const void* __restrict__ eu2,
                        const void* __restrict__ eu3, const void* __restrict__ ed1,
                        const void* __restrict__ ed2, const void* __restrict__ ed3,
                        float* __restrict__ mu, float* __restrict__ md,
                        int2* __restrict__ bse_a, ushort_t* __restrict__ bse_w3) {
    extern __shared__ char dynlds[];
    int2* ssA      = (int2*)dynlds;               // CH*8  sorted (src|local<<24, w1|w2)
    ushort_t* ssW  = (ushort_t*)(ssA + CH);       // CH*2  w3
    ushort_t* sbkt = ssW + CH;                    // CH*2  bucket id
    int* h    = (int*)(sbkt + CH);                // NBp
    int* lofs = h + NBp;                          // NBp
    int* cur  = lofs + NBp;                       // NBp
    int* gb   = cur + NBp;                        // NBp
    int tid = threadIdx.x;
    int cidx = blockIdx.x;
    int dir = blockIdx.y;
    int is64 = flags[16];
    const void* w1p = dir ? ed1 : eu1;
    const void* w2p = dir ? ed2 : eu2;
    const void* w3p = dir ? ed3 : eu3;
    float* mout = dir ? md : mu;
    int f1 = flags[dir ? 5 : 4], f2 = flags[dir ? 10 : 9], f3 = flags[dir ? 15 : 14];
    for (int i = tid; i < NBp; i += 512) { h[i] = 0; cur[i] = 0; }
    // deterministic global base for this (chunk,dir): no atomics, no dependency
    for (int b = tid; b < NB; b += 512)
        gb[b] = bb[dir * (NBMAX + 1) + b] + hc[((long)dir * NC + cidx) * NB + b];
    __syncthreads();
    long base = (long)cidx * CH;
    const int EPT = CH / 512;   // 5
    int myd[EPT], mys[EPT], myw12[EPT];
    ushort_t myw3[EPT];
#pragma unroll
    for (int i = 0; i < EPT; i++) {
        long e = base + i * 512 + tid;
        myd[i] = -1;
        if (e < E) {
            myd[i] = lde(ei, dir ? 0 : 1, e, E, is64);
            mys[i] = lde(ei, dir ? 1 : 0, e, E, is64);
            float v1 = ldf(w1p, e, f1);
            float v2 = ldf(w2p, e, f2);
            float v3 = ldf(w3p, e, f3);
            myw12[i] = (unsigned)f2u(v1) | ((unsigned)f2u(v2) << 16);
            myw3[i] = f2u(v3);
            mout[e] = (v1 + v2 + v3) / 3.0f;
            atomicAdd(&h[myd[i] >> BSH], 1);
        }
    }
    __syncthreads();
    // single-wave exclusive scan of h[0..NBp) -> lofs
    if (tid < 64) {
        int carry = 0;
        for (int g = 0; g < NBp; g += 64) {
            int idx = g + tid;
            int v = (idx < NBp) ? h[idx] : 0;
            int x = v;
#pragma unroll
            for (int o = 1; o < 64; o <<= 1) {
                int y = __shfl_up(x, o, 64);
                if (tid >= o) x += y;
            }
            if (idx < NBp) lofs[idx] = x - v + carry;
            carry += __shfl(x, 63, 64);
        }
    }
    __syncthreads();
#pragma unroll
    for (int i = 0; i < EPT; i++) {
        if (myd[i] >= 0) {
            int b = myd[i] >> BSH;
            int r = atomicAdd(&cur[b], 1);
            int p = lofs[b] + r;
            ssA[p] = make_int2(mys[i] | ((myd[i] & 255) << 24), myw12[i]);
            ssW[p] = myw3[i];
            sbkt[p] = (ushort_t)b;
        }
    }
    __syncthreads();
    long rem = E - base;
    int nvalid = rem >= CH ? CH : (rem > 0 ? (int)rem : 0);
    int2* osA = bse_a + (long)dir * E;
    ushort_t* osW = bse_w3 + (long)dir * E;
    for (int s = tid; s < nvalid; s += 512) {
        int b = sbkt[s];
        long p = (long)gb[b] + (s - lofs[b]);
        osA[p] = ssA[s];
        osW[p] = ssW[s];
    }
}

// Per-(bucket,dir) counting sort into final per-node CSR. Sorted bucket staged
// in LDS (two half-passes over locals <128/>=128), then written out coalesced:
// list + the 3 CSR-ordered bf16 weight tables. No random global writes.
// 512 threads; single-wave shfl scan.
__global__ __launch_bounds__(512) void kb_csr(
                       const int* __restrict__ bb, const int2* __restrict__ bse_a,
                       const ushort_t* __restrict__ bse_w3,
                       long E, int NB, long N,
                       int* __restrict__ off_c, int* __restrict__ off_r,
                       int* __restrict__ list_c, int* __restrict__ list_r,
                       ushort_t* __restrict__ wc6) {
    __shared__ int2 sA[CSRCAP];         // 48 KB
    __shared__ ushort_t sW[CSRCAP];     // 12 KB
    __shared__ int h[256], lofs[256], cur[256];
    int tid = threadIdx.x;
    int b = blockIdx.x, dir = blockIdx.y;
    int base = bb[dir * (NBMAX + 1) + b];
    int cnt  = bb[dir * (NBMAX + 1) + b + 1] - base;
    const int2* bsA = bse_a + (long)dir * E;
    const ushort_t* bsW = bse_w3 + (long)dir * E;
    int* off  = dir ? off_r : off_c;
    int* list = dir ? list_r : list_c;
    ushort_t* o1 = wc6 + (long)(0 + dir) * E;   // layer1 (y = 2L+dir)
    ushort_t* o2 = wc6 + (long)(2 + dir) * E;   // layer2
    ushort_t* o3 = wc6 + (long)(4 + dir) * E;   // layer3
    if (tid < 256) { h[tid] = 0; cur[tid] = 0; }
    __syncthreads();
    int nb0 = b << BSH;
    for (int s = tid; s < cnt; s += 512)
        atomicAdd(&h[(unsigned)bsA[base + s].x >> 24], 1);
    __syncthreads();
    if (tid < 64) {
        int carry = 0;
#pragma unroll
        for (int g = 0; g < 4; g++) {
            int idx = g * 64 + tid;
            int v = h[idx];
            int x = v;
#pragma unroll
            for (int o = 1; o < 64; o <<= 1) {
                int y = __shfl_up(x, o, 64);
                if (tid >= o) x += y;
            }
            lofs[idx] = x - v + carry;
            carry += __shfl(x, 63, 64);
        }
    }
    __syncthreads();
    if (tid < 256) {
        long n = (long)nb0 + tid;
        if (n < N) off[n] = base + lofs[tid];
    }
    if (b == 0 && tid == 0) off[N] = (int)E;
    int mid = lofs[128];
    int cnt1 = cnt - mid;
    if (mid <= CSRCAP && cnt1 <= CSRCAP) {
        for (int s = tid; s < cnt; s += 512) {
            int2 se = bsA[base + s];
            int local = (unsigned)se.x >> 24;
            if (local < 128) {
                int r = atomicAdd(&cur[local], 1);
                int p = lofs[local] + r;
                sA[p] = se;
                sW[p] = bsW[base + s];
            }
        }
        __syncthreads();
        for (int s = tid; s < mid; s += 512) {
            int2 se = sA[s];
            list[base + s] = se.x & 0xFFFFFF;
            o1[base + s] = (ushort_t)((unsigned)se.y & 0xFFFF);
            o2[base + s] = (ushort_t)((unsigned)se.y >> 16);
            o3[base + s] = sW[s];
        }
        __syncthreads();
        for (int s = tid; s < cnt; s += 512) {
            int2 se = bsA[base + s];
            int local = (unsigned)se.x >> 24;
            if (local >= 128) {
                int r = atomicAdd(&cur[local], 1);
                int p = lofs[local] - mid + r;
                sA[p] = se;
                sW[p] = bsW[base + s];
            }
        }
        __syncthreads();
        for (int s = tid; s < cnt1; s += 512) {
            int2 se = sA[s];
            list[base + mid + s] = se.x & 0xFFFFFF;
            o1[base + mid + s] = (ushort_t)((unsigned)se.y & 0xFFFF);
            o2[base + mid + s] = (ushort_t)((unsigned)se.y >> 16);
            o3[base + mid + s] = sW[s];
        }
    } else {
        for (int s = tid; s < cnt; s += 512) {
            int2 se = bsA[base + s];
            int local = (unsigned)se.x >> 24;
            int r = atomicAdd(&cur[local], 1);
            long p = (long)base + lofs[local] + r;
            list[p] = se.x & 0xFFFFFF;
            o1[p] = (ushort_t)((unsigned)se.y & 0xFFFF);
            o2[p] = (ushort_t)((unsigned)se.y >> 16);
            o3[p] = bsW[base + s];
        }
    }
}

// ================================================================ phase-split gather (F==32)
// EIGHT NODES PER WAVE (8 lanes each): 2 edge-subs x 4 feature-lanes per node;
// each lane loads uint4 (8 bf16 = 16B), 4 edges pipelined. The node-packing
// knob paid in r11/r13/r14 (456.7 -> 438.2 -> 424.1): fewer waves, fewer
// reduction stages (now ONE xor), less list/wc replication, fewer idle tails.
// One random table per dispatch -> per-XCD L2-resident (dual-table thrashed).
__device__ __forceinline__ void gedge1(const int* __restrict__ list, const ushort_t* __restrict__ wc,
                                       const ushort_t* __restrict__ S, int j, int f8,
                                       float* a) {
    int s0 = list[j];
    float w0 = u2f(wc[j]);
    uint4 p0 = *(const uint4*)&S[((long)s0 << 5) + f8];
    a[0] += w0 * lo2f(p0.x); a[1] += w0 * hi2f(p0.x);
    a[2] += w0 * lo2f(p0.y); a[3] += w0 * hi2f(p0.y);
    a[4] += w0 * lo2f(p0.z); a[5] += w0 * hi2f(p0.z);
    a[6] += w0 * lo2f(p0.w); a[7] += w0 * hi2f(p0.w);
}
// 2 subs per node: sub in [0,2), len = ceil(deg/2).
__device__ __forceinline__ void gacc2(const int* __restrict__ list, const ushort_t* __restrict__ wc,
                                      const ushort_t* __restrict__ S, int j0, int j1, int sub, int f8,
                                      float* a) {
    int deg = j1 - j0;
    int len = (deg + 1) >> 1;
    int j = j0 + sub * len;
    int je = j + len; if (je > j1) je = j1;
    if (j < je && (j & 1)) { gedge1(list, wc, S, j, f8, a); j++; }
    for (; j + 3 < je; j += 4) {       // 4 edges, 4 random lines in flight
        int2 s01 = *(const int2*)&list[j];
        int2 s23 = *(const int2*)&list[j + 2];
        uint_t w01 = *(const uint_t*)&wc[j];
        uint_t w23 = *(const uint_t*)&wc[j + 2];
        uint4 p0 = *(const uint4*)&S[((long)s01.x << 5) + f8];
        uint4 p1 = *(const uint4*)&S[((long)s01.y << 5) + f8];
        uint4 p2 = *(const uint4*)&S[((long)s23.x << 5) + f8];
        uint4 p3 = *(const uint4*)&S[((long)s23.y << 5) + f8];
        float w0 = lo2f(w01), w1 = hi2f(w01), w2 = lo2f(w23), w3 = hi2f(w23);
        a[0] += w0 * lo2f(p0.x) + w1 * lo2f(p1.x) + w2 * lo2f(p2.x) + w3 * lo2f(p3.x);
        a[1] += w0 * hi2f(p0.x) + w1 * hi2f(p1.x) + w2 * hi2f(p2.x) + w3 * hi2f(p3.x);
        a[2] += w0 * lo2f(p0.y) + w1 * lo2f(p1.y) + w2 * lo2f(p2.y) + w3 * lo2f(p3.y);
        a[3] += w0 * hi2f(p0.y) + w1 * hi2f(p1.y) + w2 * hi2f(p2.y) + w3 * hi2f(p3.y);
        a[4] += w0 * lo2f(p0.z) + w1 * lo2f(p1.z) + w2 * lo2f(p2.z) + w3 * lo2f(p3.z);
        a[5] += w0 * hi2f(p0.z) + w1 * hi2f(p1.z) + w2 * hi2f(p2.z) + w3 * hi2f(p3.z);
        a[6] += w0 * lo2f(p0.w) + w1 * lo2f(p1.w) + w2 * lo2f(p2.w) + w3 * lo2f(p3.w);
        a[7] += w0 * hi2f(p0.w) + w1 * hi2f(p1.w) + w2 * hi2f(p2.w) + w3 * hi2f(p3.w);
    }
    if (j + 1 < je) {                  // 2 edges
        int2 s01 = *(const int2*)&list[j];
        uint_t w01 = *(const uint_t*)&wc[j];
        uint4 p0 = *(const uint4*)&S[((long)s01.x << 5) + f8];
        uint4 p1 = *(const uint4*)&S[((long)s01.y << 5) + f8];
        float w0 = lo2f(w01), w1 = hi2f(w01);
        a[0] += w0 * lo2f(p0.x) + w1 * lo2f(p1.x);
        a[1] += w0 * hi2f(p0.x) + w1 * hi2f(p1.x);
        a[2] += w0 * lo2f(p0.y) + w1 * lo2f(p1.y);
        a[3] += w0 * hi2f(p0.y) + w1 * hi2f(p1.y);
        a[4] += w0 * lo2f(p0.z) + w1 * lo2f(p1.z);
        a[5] += w0 * hi2f(p0.z) + w1 * hi2f(p1.z);
        a[6] += w0 * lo2f(p0.w) + w1 * lo2f(p1.w);
        a[7] += w0 * hi2f(p0.w) + w1 * hi2f(p1.w);
        j += 2;
    }
    if (j < je) gedge1(list, wc, S, j, f8, a);
}

// Phase A: up-direction (col-CSR over Su) -> U[n][32] fp32 (deg-normalized).
__global__ void k_gather_up(const int* __restrict__ off_c, const int* __restrict__ list_c,
                            const ushort_t* __restrict__ wcu, const ushort_t* __restrict__ Su,
                            long N, float* __restrict__ U) {
    long t = (long)blockIdx.x * blockDim.x + threadIdx.x;
    long oct = t >> 6;
    int lane = (int)(t & 63);
    long n = oct * 8 + (lane >> 3);
    if (n >= N) return;
    int hl = lane & 7;
    int sub = hl >> 2;       // 0..1
    int f8  = (hl & 3) << 3; // element offset 0,8,16,24
    int j0 = off_c[n], j1 = off_c[n + 1];
    float a[8] = {0.f, 0.f, 0.f, 0.f, 0.f, 0.f, 0.f, 0.f};
    gacc2(list_c, wcu, Su, j0, j1, sub, f8, a);
#pragma unroll
    for (int k = 0; k < 8; k++)
        a[k] += __shfl_xor(a[k], 4, 8);
    if (sub == 0) {
        int deg = j1 - j0;
        float dinv = (deg > 0) ? 1.0f / (float)deg : 0.f;
        *(float4*)&U[(n << 5) + f8] =
            make_float4(a[0] * dinv, a[1] * dinv, a[2] * dinv, a[3] * dinv);
        *(float4*)&U[(n << 5) + f8 + 4] =
            make_float4(a[4] * dinv, a[5] * dinv, a[6] * dinv, a[7] * dinv);
    }
}

// Phase B: down-direction (row-CSR over Sd) + U + Sb -> normalize+leaky -> out.
__global__ void k_gather_downfin(const int* __restrict__ off_r, const int* __restrict__ list_r,
                                 const ushort_t* __restrict__ wcd, const ushort_t* __restrict__ Sd,
                                 const ushort_t* __restrict__ Sb, const float* __restrict__ U,
                                 long N, float* __restrict__ out) {
    long t = (long)blockIdx.x * blockDim.x + threadIdx.x;
    long oct = t >> 6;
    int lane = (int)(t & 63);
    long n = oct * 8 + (lane >> 3);
    if (n >= N) return;
    int hl = lane & 7;
    int sub = hl >> 2;
    int f8  = (hl & 3) << 3;
    int j0 = off_r[n], j1 = off_r[n + 1];
    float a[8] = {0.f, 0.f, 0.f, 0.f, 0.f, 0.f, 0.f, 0.f};
    gacc2(list_r, wcd, Sd, j0, j1, sub, f8, a);
#pragma unroll
    for (int k = 0; k < 8; k++)
        a[k] += __shfl_xor(a[k], 4, 8);
    float v[8], u[8], c[8];
    float ss = 0.f;
    if (sub == 0) {
        int deg = j1 - j0;
        float dinv = (deg > 0) ? 1.0f / (float)deg : 0.f;
#pragma unroll
        for (int k = 0; k < 8; k++) { v[k] = a[k] * dinv; ss += v[k] * v[k]; }
        float4 uv0 = *(const float4*)&U[(n << 5) + f8];
        float4 uv1 = *(const float4*)&U[(n << 5) + f8 + 4];
        u[0] = uv0.x; u[1] = uv0.y; u[2] = uv0.z; u[3] = uv0.w;
        u[4] = uv1.x; u[5] = uv1.y; u[6] = uv1.z; u[7] = uv1.w;
#pragma unroll
        for (int k = 0; k < 8; k++) ss += u[k] * u[k];
        uint4 bp = *(const uint4*)&Sb[(n << 5) + f8];
        c[0] = lo2f(bp.x); c[1] = hi2f(bp.x); c[2] = lo2f(bp.y); c[3] = hi2f(bp.y);
        c[4] = lo2f(bp.z); c[5] = hi2f(bp.z); c[6] = lo2f(bp.w); c[7] = hi2f(bp.w);
#pragma unroll
        for (int k = 0; k < 8; k++) ss += c[k] * c[k];
    }
#pragma unroll
    for (int m = 1; m < 8; m <<= 1) ss += __shfl_xor(ss, m, 8);
    float inv = 1.0f / fmaxf(sqrtf(ss), 1e-12f);
    if (sub == 0) {
#pragma unroll
        for (int k = 0; k < 8; k++) { float x = u[k] * inv; u[k] = (x >= 0.f) ? x : 0.1f * x; }
#pragma unroll
        for (int k = 0; k < 8; k++) { float x = v[k] * inv; v[k] = (x >= 0.f) ? x : 0.1f * x; }
#pragma unroll
        for (int k = 0; k < 8; k++) { float x = c[k] * inv; c[k] = (x >= 0.f) ? x : 0.1f * x; }
        *(float4*)&out[n * 96 + f8]          = make_float4(u[0], u[1], u[2], u[3]);
        *(float4*)&out[n * 96 + f8 + 4]      = make_float4(u[4], u[5], u[6], u[7]);
        *(float4*)&out[n * 96 + 32 + f8]     = make_float4(v[0], v[1], v[2], v[3]);
        *(float4*)&out[n * 96 + 32 + f8 + 4] = make_float4(v[4], v[5], v[6], v[7]);
        *(float4*)&out[n * 96 + 64 + f8]     = make_float4(c[0], c[1], c[2], c[3]);
        *(float4*)&out[n * 96 + 64 + f8 + 4] = make_float4(c[4], c[5], c[6], c[7]);
    }
}

// ================================================================ specialized linear, din=96, dout=3x32 fused: MFMA
// mfma_f32_16x16x32_bf16, 64 nodes/block, 4 waves, 18 MFMA/wave. W staged in
// LDS pre-swizzled into B-fragment order; A rows bf16 padded to 104.
// C/D layout: col=lane&15, row=(lane>>4)*4+reg (HW-verified).
__global__ __launch_bounds__(256) void k_lin96(
                        const float* __restrict__ xin, long N,
                        const void* __restrict__ wu, const void* __restrict__ wd,
                        const void* __restrict__ wb, int wfi,
                        const int* __restrict__ flags,
                        ushort_t* __restrict__ Su, ushort_t* __restrict__ Sd,
                        ushort_t* __restrict__ Sb) {
    __shared__ ushort_t wlds[6 * 3 * 64 * 8];   // 18 KB: B-frags, [ntile][kstep][lane][8]
    __shared__ ushort_t alds[64 * 104];         // 13.3 KB: A rows bf16, stride 104
    int tid = threadIdx.x;
    int ubf = flags[wfi], dbf = flags[wfi + 1], bbf = flags[wfi + 2];
    // stage W: slot (t,s,l) holds W[k = s*32 + (l>>4)*8 + j][n = t*16 + (l&15)]
    for (int idx = tid; idx < 6 * 3 * 64; idx += 256) {
        int t = idx / (3 * 64);
        int rem = idx - t * 3 * 64;
        int s = rem >> 6;
        int l = rem & 63;
        int n = t * 16 + (l & 15);
        int kg = l >> 4;
        const void* w = (n < 32) ? wu : (n < 64) ? wd : wb;
        int f = (n < 32) ? ubf : (n < 64) ? dbf : bbf;
        int o = n & 31;
        ushort_t tmp[8];
#pragma unroll
        for (int j = 0; j < 8; j++)
            tmp[j] = f2u(ldf(w, (long)o * 96 + s * 32 + kg * 8 + j, f));
        *(bf16x8*)&wlds[idx * 8] = *(const bf16x8*)tmp;
    }
    long nb = (long)blockIdx.x * 64;
    for (int j = tid; j < 64 * 24; j += 256) {   // 1536 float4, coalesced
        int node = j / 24, c = j % 24;
        long gn = nb + node;
        float4 v = make_float4(0.f, 0.f, 0.f, 0.f);
        if (gn < N) v = ((const float4*)(xin + gn * 96))[c];
        ushort_t* dst = &alds[node * 104 + c * 4];
        dst[0] = f2u(v.x); dst[1] = f2u(v.y); dst[2] = f2u(v.z); dst[3] = f2u(v.w);
    }
    __syncthreads();
    int wv = tid >> 6;          // wave 0..3 -> rows wv*16..wv*16+15
    int lane = tid & 63;
    int m0 = lane & 15;
    int kg = lane >> 4;
    int row = wv * 16 + m0;
    f32x4 acc[6];
#pragma unroll
    for (int t = 0; t < 6; t++) acc[t] = (f32x4){0.f, 0.f, 0.f, 0.f};
#pragma unroll
    for (int s = 0; s < 3; s++) {
        bf16x8 a = *(const bf16x8*)&alds[row * 104 + s * 32 + kg * 8];
#pragma unroll
        for (int t = 0; t < 6; t++) {
            bf16x8 b = *(const bf16x8*)&wlds[((t * 3 + s) * 64 + lane) * 8];
            acc[t] = __builtin_amdgcn_mfma_f32_16x16x32_bf16(a, b, acc[t], 0, 0, 0);
        }
    }
    __syncthreads();                       // all A reads done; reuse alds as C staging
    ushort_t* sbuf = alds;                 // 64*96 = 6144 ushorts < 64*104
#pragma unroll
    for (int t = 0; t < 6; t++) {
        int n = t * 16 + (lane & 15);
#pragma unroll
        for (int r = 0; r < 4; r++) {
            int m = (lane >> 4) * 4 + r;
            sbuf[(wv * 16 + m) * 96 + n] = f2u(acc[t][r]);
        }
    }
    __syncthreads();
    for (int j = tid; j < 64 * 96; j += 256) {
        int nd = j / 96, o3 = j % 96;
        long gn = nb + nd;
        if (gn < N) {
            int blk = o3 >> 5, fo = o3 & 31;
            ushort_t v = sbuf[j];
            (blk == 0 ? Su : blk == 1 ? Sd : Sb)[gn * 32 + fo] = v;
        }
    }
}

// ================================================================ generic linear -> bf16 S arrays (layer 1)
__global__ void k_linear_b16(const void* __restrict__ xin, int xfi, int din, int dout, long N,
                             const void* __restrict__ wu, const void* __restrict__ wd,
                             const void* __restrict__ wb, int wfi,
                             const int* __restrict__ flags, int uselds,
                             ushort_t* __restrict__ Su, ushort_t* __restrict__ Sd,
                             ushort_t* __restrict__ Sb) {
    __shared__ float smem[12288];
    int xbf = (xfi >= 0) ? flags[xfi] : 0;
    int ubf = flags[wfi], dbf = flags[wfi + 1], bbf = flags[wfi + 2];
    float* su = smem;
    float* sd = smem + (long)din * dout;
    float* sb = smem + 2l * din * dout;
    if (uselds) {
        for (int j = threadIdx.x; j < din * dout; j += 256) {
            int o = j % dout, i = j / dout;
            su[j] = ldf(wu, (long)o * din + i, ubf);
            sd[j] = ldf(wd, (long)o * din + i, dbf);
            sb[j] = ldf(wb, (long)o * din + i, bbf);
        }
        __syncthreads();
    }
    long idx = (long)blockIdx.x * blockDim.x + threadIdx.x;
    long node = idx / dout;
    int o = (int)(idx % dout);
    if (node >= N) return;
    float au = 0.f, ad = 0.f, ab = 0.f;
    long xb = node * din;
    if (uselds) {
        for (int i = 0; i < din; i++) {
            float xv = ldf(xin, xb + i, xbf);
            au += xv * su[i * dout + o];
            ad += xv * sd[i * dout + o];
            ab += xv * sb[i * dout + o];
        }
    } else {
        for (int i = 0; i < din; i++) {
            float xv = ldf(xin, xb + i, xbf);
            au += xv * ldf(wu, (long)o * din + i, ubf);
            ad += xv * ldf(wd, (long)o * din + i, dbf);
            ab += xv * ldf(wb, (long)o * din + i, bbf);
        }
    }
    Su[node * dout + o] = f2u(au);
    Sd[node * dout + o] = f2u(ad);
    Sb[node * dout + o] = f2u(ab);
}

// ================================================================ fallback (round-4 proven) kernels
__global__ void k_linear(const void* __restrict__ xin, int xfi, int din, int dout, int rs, long N,
                         const void* __restrict__ wu, const void* __restrict__ wd,
                         const void* __restrict__ wb, int wfi,
                         const int* __restrict__ flags, int uselds,
                         float* __restrict__ A, float* __restrict__ B, float* __restrict__ C) {
    __shared__ float smem[12288];
    int xbf = (xfi >= 0) ? flags[xfi] : 0;
    int ubf = flags[wfi], dbf = flags[wfi + 1], bbf = flags[wfi + 2];
    float* su = smem;
    float* sd = smem + (long)din * dout;
    float* sb = smem + 2l * din * dout;
    if (uselds) {
        for (int j = threadIdx.x; j < din * dout; j += 256) {
            int o = j % dout, i = j / dout;
            su[j] = ldf(wu, (long)o * din + i, ubf);
            sd[j] = ldf(wd, (long)o * din + i, dbf);
            sb[j] = ldf(wb, (long)o * din + i, bbf);
        }
        __syncthreads();
    }
    long idx = (long)blockIdx.x * blockDim.x + threadIdx.x;
    long node = idx / dout;
    int o = (int)(idx % dout);
    if (node >= N) return;
    float au = 0.f, ad = 0.f, ab = 0.f;
    long xb = node * din;
    if (uselds) {
        for (int i = 0; i < din; i++) {
            float xv = ldf(xin, xb + i, xbf);
            au += xv * su[i * dout + o];
            ad += xv * sd[i * dout + o];
            ab += xv * sb[i * dout + o];
        }
    } else {
        for (int i = 0; i < din; i++) {
            float xv = ldf(xin, xb + i, xbf);
            au += xv * ldf(wu, (long)o * din + i, ubf);
            ad += xv * ldf(wd, (long)o * din + i, dbf);
            ab += xv * ldf(wb, (long)o * din + i, bbf);
        }
    }
    A[node * rs + o] = au;
    B[node * rs + o] = ad;
    C[node * rs + o] = ab;
}

__global__ void k_deg(const int* __restrict__ ei, long E, const int* __restrict__ flags,
                      float* __restrict__ degc, float* __restrict__ degr) {
    long e = (long)blockIdx.x * blockDim.x + threadIdx.x;
    if (e < E) {
        int is64 = flags[16];
        atomicAdd(&degc[lde(ei, 1, e, E, is64)], 1.0f);
        atomicAdd(&degr[lde(ei, 0, e, E, is64)], 1.0f);
    }
}

__global__ void k_inv(float* __restrict__ a, long n) {
    long i = (long)blockIdx.x * blockDim.x + threadIdx.x;
    if (i < n) { float v = a[i]; a[i] = (v > 0.0f) ? 1.0f / v : 0.0f; }
}

__global__ void k_scatter(const int* __restrict__ ei, long E, int F,
                          const void* __restrict__ ewu, const void* __restrict__ ewd,
                          int fu, int fd, const int* __restrict__ flags,
                          const float* __restrict__ degci, const float* __restrict__ degri,
                          const float* __restrict__ A, const float* __restrict__ B,
                          float* __restrict__ U, float* __restrict__ D) {
    long idx = (long)blockIdx.x * blockDim.x + threadIdx.x;
    long tot = E * 2 * F;
    if (idx >= tot) return;
    int is64 = flags[16];
    long e = idx / (2 * F);
    int rem = (int)(idx - e * 2 * F);
    int dir = rem >= F;
    int f = rem - dir * F;
    int r = lde(ei, 0, e, E, is64), c = lde(ei, 1, e, E, is64);
    if (!dir) {
        float w = degci[c] * ldf(ewu, e, flags[fu]);
        atomicAdd(&U[(long)c * F + f], w * A[(long)r * F + f]);
    } else {
        float w = degri[r] * ldf(ewd, e, flags[fd]);
        atomicAdd(&D[(long)r * F + f], w * B[(long)c * F + f]);
    }
}

__global__ void k_finalize(const float* __restrict__ U, const float* __restrict__ D,
                           const float* __restrict__ C, int F, long N,
                           float* __restrict__ out) {
    long t = (long)blockIdx.x * blockDim.x + threadIdx.x;
    long n = t >> 6;
    if (n >= N) return;
    int lane = (int)(t & 63);
    int cat = 3 * F;
    float ss = 0.f;
    for (int j = lane; j < cat; j += 64) {
        float v = (j < F) ? U[n * F + j] : (j < 2 * F) ? D[n * F + j - F] : C[n * F + j - 2 * F];
        ss += v * v;
    }
#pragma unroll
    for (int m = 1; m < 64; m <<= 1) ss += __shfl_xor(ss, m, 64);
    float inv = 1.0f / fmaxf(sqrtf(ss), 1e-12f);
    for (int j = lane; j < cat; j += 64) {
        float v = (j < F) ? U[n * F + j] : (j < 2 * F) ? D[n * F + j - F] : C[n * F + j - 2 * F];
        float a = v * inv;
        a = (a >= 0.0f) ? a : 0.1f * a;
        out[n * cat + j] = a;
    }
}

__global__ void k_mean(const void* e1u, const void* e2u, const void* e3u,
                       const void* e1d, const void* e2d, const void* e3d,
                       const int* __restrict__ flags, long E,
                       float* __restrict__ mu, float* __restrict__ md) {
    long e = (long)blockIdx.x * blockDim.x + threadIdx.x;
    if (e >= E) return;
    float su = ldf(e1u, e, flags[4]) + ldf(e2u, e, flags[9]) + ldf(e3u, e, flags[14]);
    float sd = ldf(e1d, e, flags[5]) + ldf(e2d, e, flags[10]) + ldf(e3d, e, flags[15]);
    mu[e] = su / 3.0f;
    md[e] = sd / 3.0f;
}

extern "C" void kernel_launch(void* const* d_in, const int* in_sizes, int n_in,
                              void* d_out, int out_size, void* d_ws, size_t ws_size,
                              hipStream_t stream) {
    const int* ei = (const int*)d_in[1];
    const void* w_up[3]   = {d_in[2], d_in[7],  d_in[12]};
    const void* w_down[3] = {d_in[3], d_in[8],  d_in[13]};
    const void* w_bias[3] = {d_in[4], d_in[9],  d_in[14]};
    const void* ew_up[3]  = {d_in[5], d_in[10], d_in[15]};
    const void* ew_down[3]= {d_in[6], d_in[11], d_in[16]};

    // ---- derive true sizes from in_sizes
    long E = in_sizes[5];
    if (E <= 0) E = 1600000;
    int HID = (int)(sqrt((double)in_sizes[7] / 3.0) + 0.5);
    if (HID <= 0 || (long)3 * HID * HID != (long)in_sizes[7]) HID = 32;
    int DIN = in_sizes[2] / HID;
    if (DIN <= 0) DIN = 8;
    long N = (long)in_sizes[0] / DIN;
    if (N <= 0) N = 50000;
    int EMB = in_sizes[12] / (3 * HID);
    if (EMB <= 0) EMB = 32;
    int Fm = HID > EMB ? HID : EMB;
    int NB = (int)((N + 255) >> BSH);
    int NBp = (NB + 1) & ~1;
    int NC = (int)((E + CH - 1) / CH);

    // ---- outputs: fp32, concatenated (h, mean_up, mean_down)
    float* out_h  = (float*)d_out;
    float* out_mu = out_h + N * 3l * EMB;
    float* out_md = out_mu + E;

    const int TB = 256;
    int lds1  = (3l * DIN * HID <= 12288) ? 1 : 0;
    int lds12 = (3l * (3 * HID) * HID <= 12288) ? 1 : 0;
    int lds3  = (3l * (3 * HID) * EMB <= 12288) ? 1 : 0;
    dim3 linG1((unsigned)((N * HID + TB - 1) / TB));
    dim3 linG3((unsigned)((N * EMB + TB - 1) / TB));
    dim3 lin96G((unsigned)((N + 63) / 64));
    dim3 finG((unsigned)((N * 64 + TB - 1) / TB));
    long noct = (N + 7) / 8;
    dim3 finG8((unsigned)((noct * 64 + TB - 1) / TB));
    dim3 edgeG((unsigned)((E + TB - 1) / TB));
    dim3 chunkG1((unsigned)NC);
    dim3 chunkG2((unsigned)NC, 2);
    size_t fillLds = (size_t)CH * 12 + (size_t)(4 * NBp) * 4;

    // ---- fast-path workspace layout
    int* flags = (int*)d_ws;                       // 64
    int* bc    = flags + 64;                       // 2*NBMAX
    int* bb    = bc + 2 * NBMAX;                   // 2*(NBMAX+1)
    int* off_c = bb + 2 * (NBMAX + 1);             // N+1
    int* off_r = off_c + (N + 1);                  // N+1
    int* hc    = off_r + (N + 1);                  // 2*NC*NB per-chunk hist/prefix
    long li = (long)(hc + 2l * NC * NB - (int*)d_ws);
    li = (li + 3) & ~3l;
    int* list_c = (int*)d_ws + li;                 // E (src only - gather hot path)
    int* list_r = list_c + E;                      // E
    ushort_t* wc6 = (ushort_t*)(list_r + E);       // 6E ushorts = 3E ints (CSR weights)
    int* X = list_r + E + 3 * E;                   // overlay region
    // phase 1 (bucket build): bse_a 2E int2 = 4E ints, bse_w3 2E ushorts = E ints
    int2* bse_a = (int2*)X;
    ushort_t* bse_w3 = (ushort_t*)(X + 4 * E);
    // phase 2+: S/U arrays overlay X (bse dead after kb_csr)
    ushort_t* Su = (ushort_t*)X;                   // N*Fm
    ushort_t* Sd = Su + N * Fm;
    ushort_t* Sb = Sd + N * Fm;
    float* U = (float*)(Sb + N * Fm);              // N*Fm fp32 (int-aligned: 3*N*Fm even)
    long zInts = (3l * N * Fm + 1) / 2 + N * Fm;   // S arrays + U
    long Xints = 5l * E;                           // phase 1 (bse_a + bse_w3)
    if (zInts > Xints) Xints = zInts;
    size_t need = (size_t)((li + 5l * E + Xints) * 4l + 256);

    bool fast = (HID == 32 && EMB == 32) && (NB <= NBMAX) && (NC <= NCMAX) &&
                (ws_size == 0 || ws_size >= need);

    // ---- dtype detection (both paths)
    DetectArgs da;
    da.p[0] = d_in[0]; da.n[0] = in_sizes[0];
    for (int L = 0; L < 3; L++) {
        da.p[1 + 5 * L] = w_up[L];    da.n[1 + 5 * L] = in_sizes[2 + 5 * L];
        da.p[2 + 5 * L] = w_down[L];  da.n[2 + 5 * L] = in_sizes[3 + 5 * L];
        da.p[3 + 5 * L] = w_bias[L];  da.n[3 + 5 * L] = in_sizes[4 + 5 * L];
        da.p[4 + 5 * L] = ew_up[L];   da.n[4 + 5 * L] = in_sizes[5 + 5 * L];
        da.p[5 + 5 * L] = ew_down[L]; da.n[5 + 5 * L] = in_sizes[6 + 5 * L];
    }
    da.ei = ei; da.E = E; da.flags = flags;
    k_detect<<<17, TB, 0, stream>>>(da);

    if (fast) {
        // ---- bucketed CSR build, deterministic bases (no global atomics);
        //      kb_fill also writes the mean outputs (fused, one pass)
        kb_count<<<chunkG1, TB, 0, stream>>>(ei, E, flags, NB, NC, hc);
        kb_scanA<<<dim3((unsigned)NB, 2), 256, 0, stream>>>(hc, NC, NB, bc);
        kb_scanB<<<1, 64, 0, stream>>>(bc, bb, NB);
        kb_fill<<<chunkG2, 512, fillLds, stream>>>(ei, E, flags, NB, NBp, NC, hc, bb,
                                                   ew_up[0], ew_up[1], ew_up[2],
                                                   ew_down[0], ew_down[1], ew_down[2],
                                                   out_mu, out_md,
                                                   bse_a, bse_w3);
        kb_csr<<<dim3((unsigned)NB, 2), 512, 0, stream>>>(bb, bse_a, bse_w3, E, NB, N,
                                                          off_c, off_r, list_c, list_r,
                                                          wc6);

        float* H = (float*)d_out;   // intermediate 96-wide activations live in d_out

        // ---- layer 1 (din=DIN, generic, bf16 S output)
        k_linear_b16<<<linG1, TB, 0, stream>>>(d_in[0], 0, DIN, HID, N,
                                               w_up[0], w_down[0], w_bias[0], 1, flags, lds1,
                                               Su, Sd, Sb);
        k_gather_up<<<finG8, TB, 0, stream>>>(off_c, list_c, wc6, Su, N, U);
        k_gather_downfin<<<finG8, TB, 0, stream>>>(off_r, list_r, wc6 + E, Sd, Sb, U, N, H);
        // ---- layer 2 (din=96 MFMA)
        k_lin96<<<lin96G, 256, 0, stream>>>(H, N, w_up[1], w_down[1], w_bias[1], 6, flags,
                                            Su, Sd, Sb);
        k_gather_up<<<finG8, TB, 0, stream>>>(off_c, list_c, wc6 + 2l * E, Su, N, U);
        k_gather_downfin<<<finG8, TB, 0, stream>>>(off_r, list_r, wc6 + 3l * E, Sd, Sb, U, N, H);
        // ---- layer 3 -> final fp32 output
        k_lin96<<<lin96G, 256, 0, stream>>>(H, N, w_up[2], w_down[2], w_bias[2], 11, flags,
                                            Su, Sd, Sb);
        k_gather_up<<<finG8, TB, 0, stream>>>(off_c, list_c, wc6 + 4l * E, Su, N, U);
        k_gather_downfin<<<finG8, TB, 0, stream>>>(off_r, list_r, wc6 + 5l * E, Sd, Sb, U, N, out_h);
    } else {
        // ---- fallback: round-4 proven atomic-scatter path
        float* degci = (float*)(flags + 64);
        float* degri = degci + N;
        float* fA = degri + N;
        float* fB = fA + N * Fm;
        float* fC = fB + N * Fm;
        float* fU = fC + N * Fm;
        float* fD = fU + N * Fm;
        float* fH = fD + N * Fm;
        dim3 scatG12((unsigned)((E * 2 * HID + TB - 1) / TB));
        dim3 scatG3((unsigned)((E * 2 * EMB + TB - 1) / TB));

        hipMemsetAsync(degci, 0, 2 * N * sizeof(float), stream);
        k_deg<<<edgeG, TB, 0, stream>>>(ei, E, flags, degci, degri);
        k_inv<<<dim3((unsigned)((2 * N + TB - 1) / TB)), TB, 0, stream>>>(degci, 2 * N);

        k_linear<<<linG1, TB, 0, stream>>>(d_in[0], 0, DIN, HID, HID, N,
                                           w_up[0], w_down[0], w_bias[0], 1, flags, lds1, fA, fB, fC);
        hipMemsetAsync(fU, 0, 2l * N * Fm * sizeof(float), stream);
        k_scatter<<<scatG12, TB, 0, stream>>>(ei, E, HID, ew_up[0], ew_down[0], 4, 5, flags,
                                              degci, degri, fA, fB, fU, fD);
        k_finalize<<<finG, TB, 0, stream>>>(fU, fD, fC, HID, N, fH);

        k_linear<<<linG1, TB, 0, stream>>>(fH, -1, 3 * HID, HID, HID, N,
                                           w_up[1], w_down[1], w_bias[1], 6, flags, lds12, fA, fB, fC);
        hipMemsetAsync(fU, 0, 2l * N * Fm * sizeof(float), stream);
        k_scatter<<<scatG12, TB, 0, stream>>>(ei, E, HID, ew_up[1], ew_down[1], 9, 10, flags,
                                              degci, degri, fA, fB, fU, fD);
        k_finalize<<<finG, TB, 0, stream>>>(fU, fD, fC, HID, N, fH);

        k_linear<<<linG3, TB, 0, stream>>>(fH, -1, 3 * HID, EMB, EMB, N,
                                           w_up[2], w_down[2], w_bias[2], 11, flags, lds3, fA, fB, fC);
        hipMemsetAsync(fU, 0, 2l * N * Fm * sizeof(float), stream);
        k_scatter<<<scatG3, TB, 0, stream>>>(ei, E, EMB, ew_up[2], ew_down[2], 14, 15, flags,
                                             degci, degri, fA, fB, fU, fD);
        k_finalize<<<finG, TB, 0, stream>>>(fU, fD, fC, EMB, N, out_h);

        k_mean<<<edgeG, TB, 0, stream>>>(ew_up[0], ew_up[1], ew_up[2],
                                         ew_down[0], ew_down[1], ew_down[2],
                                         flags, E, out_mu, out_md);
    }
}

// Round 16
// 422.959 us; speedup vs baseline: 1.0289x; 1.0289x over previous
//
#include <hip/hip_runtime.h>
#include <hip/hip_bf16.h>
#include <math.h>

typedef __hip_bfloat16 bf16;
typedef unsigned short ushort_t;
typedef unsigned int uint_t;
typedef __attribute__((ext_vector_type(8))) short bf16x8;
typedef __attribute__((ext_vector_type(4))) float f32x4;

#define NBMAX 1024   // max buckets (N <= 262144 for fast path; also guarantees src < 2^24)
#define BSH 8        // 256 nodes per bucket
#define CH 2560      // edges per kb_fill chunk (5/thread at 512 threads; ~34KB LDS -> 4 blocks/CU)
#define NCMAX 2048   // max chunks - kb_scanA local array bound
#define CSRCAP 6144  // LDS staging capacity per half-bucket in kb_csr (64KB -> 2 blocks/CU)

// flags[0..15]: 1 if float-array slot is bf16, 0 if fp32.
//   slot 0:x | per layer L(0..2): 1+5L:w_up 2+5L:w_down 3+5L:w_bias 4+5L:ew_up 5+5L:ew_down
// flags[16]: 1 if edge_index is int64 (little-endian, values < 2^31), else int32.
__device__ __forceinline__ float ldf(const void* p, long i, int isbf) {
    return isbf ? __bfloat162float(((const bf16*)p)[i]) : ((const float*)p)[i];
}
// int64 path: single 8B load (int2) instead of stride-2 4B load.
__device__ __forceinline__ int lde(const int* ei, int half, long e, long E, int is64) {
    long idx = half ? (E + e) : e;
    if (is64) return ((const int2*)ei)[idx].x;
    return ei[idx];
}
__device__ __forceinline__ float u2f(ushort_t u) {
    union { unsigned int i; float f; } v; v.i = ((unsigned)u) << 16; return v.f;
}
__device__ __forceinline__ ushort_t f2u(float f) {
    bf16 h = __float2bfloat16(f);
    return *reinterpret_cast<ushort_t*>(&h);
}
__device__ __forceinline__ float lo2f(unsigned sp) {
    union { unsigned i; float f; } v; v.i = sp << 16; return v.f;
}
__device__ __forceinline__ float hi2f(unsigned sp) {
    union { unsigned i; float f; } v; v.i = sp & 0xffff0000u; return v.f;
}

// ---------------------------------------------------------------- dtype detection
struct DetectArgs {
    const void* p[16];
    long n[16];
    const int* ei;
    long E;
    int* flags;
};

__global__ void k_detect(DetectArgs a) {
    __shared__ int cnt;
    if (threadIdx.x == 0) cnt = 0;
    __syncthreads();
    int b = blockIdx.x;
    int bad = 0;
    if (b < 16) {
        const bf16* p = (const bf16*)a.p[b];
        long m = a.n[b] < 4096 ? a.n[b] : 4096;
        for (long i = threadIdx.x; i < m; i += 256) {
            float v = __bfloat162float(p[i]);
            if (!(fabsf(v) < 100.0f)) bad++;
        }
        atomicAdd(&cnt, bad);
        __syncthreads();
        if (threadIdx.x == 0) a.flags[b] = ((long)cnt * 16 < m) ? 1 : 0;
    } else {
        long m = a.E / 2 < 4096 ? a.E / 2 : 4096;
        for (long i = threadIdx.x; i < m; i += 256) {
            if (a.ei[2 * i + 1] != 0) bad++;
        }
        atomicAdd(&cnt, bad);
        __syncthreads();
        if (threadIdx.x == 0) a.flags[16] = (cnt < (int)(m / 16) + 1) ? 1 : 0;
    }
}

// ================================================================ bucketed CSR build
// dir 0: dst=col (up-list), dir 1: dst=row (down-list). bucket = dst>>8.
// Weights RIDE THE SORT. Chunk write bases are DETERMINISTIC: kb_count writes
// per-chunk histograms hc[dir][chunk][b]; kb_scanA scans them across chunks;
// kb_fill reads its base directly -> zero global atomics, no RTT dependency.

// Both directions per chunk, one edge-read pass; coalesced histogram store.
__global__ void kb_count(const int* __restrict__ ei, long E, const int* __restrict__ flags,
                         int NB, int NC, int* __restrict__ hc) {
    __shared__ int h0[NBMAX], h1[NBMAX];
    for (int i = threadIdx.x; i < NB; i += 256) { h0[i] = 0; h1[i] = 0; }
    __syncthreads();
    int is64 = flags[16];
    int c = blockIdx.x;
    long base = (long)c * CH;
#pragma unroll
    for (int i = 0; i < CH / 256; i++) {
        long e = base + i * 256 + threadIdx.x;
        if (e < E) {
            int cc = lde(ei, 1, e, E, is64);   // dir0 dst=col
            int rr = lde(ei, 0, e, E, is64);   // dir1 dst=row
            atomicAdd(&h0[cc >> BSH], 1);
            atomicAdd(&h1[rr >> BSH], 1);
        }
    }
    __syncthreads();
    for (int b = threadIdx.x; b < NB; b += 256) {
        hc[((long)0 * NC + c) * NB + b] = h0[b];
        hc[((long)1 * NC + c) * NB + b] = h1[b];
    }
}

// Per-(bucket,dir): exclusive scan of hc over chunks (in place) + total -> bc.
__global__ void kb_scanA(int* __restrict__ hc, int NC, int NB, int* __restrict__ bc) {
    __shared__ int ssum[256];
    int b = blockIdx.x, d = blockIdx.y;
    int tid = threadIdx.x;
    int k = (NC + 255) / 256;          // <= 8 (NC <= NCMAX)
    int c0 = tid * k;
    int local[8];
    int s = 0;
    for (int i = 0; i < k; i++) {
        int c = c0 + i;
        int v = (c < NC) ? hc[((long)d * NC + c) * NB + b] : 0;
        local[i] = s; s += v;
    }
    ssum[tid] = s;
    __syncthreads();
    for (int dd = 1; dd < 256; dd <<= 1) {
        int t = (tid >= dd) ? ssum[tid - dd] : 0;
        __syncthreads();
        ssum[tid] += t;
        __syncthreads();
    }
    int base = ssum[tid] - s;
    for (int i = 0; i < k; i++) {
        int c = c0 + i;
        if (c < NC) hc[((long)d * NC + c) * NB + b] = base + local[i];
    }
    if (tid == 255) bc[d * NBMAX + b] = ssum[255];
}

// Bucket bases from totals (serial over NB per dir - tiny).
__global__ void kb_scanB(const int* __restrict__ bc, int* __restrict__ bb, int NB) {
    if (threadIdx.x < 2) {
        int dir = threadIdx.x;
        int acc = 0;
        for (int i = 0; i < NB; i++) { bb[dir * (NBMAX + 1) + i] = acc; acc += bc[dir * NBMAX + i]; }
        bb[dir * (NBMAX + 1) + NB] = acc;
    }
}

// Per-block counting-sort of a CH-edge chunk by bucket, bucket-contiguous
// global append at deterministic base bb[b]+hc[dir][chunk][b].
// Record: (src|local<<24, w1|w2<<16) int2 + w3 ushort.
// Also FUSES the mean outputs: dir 0 writes mu[e], dir 1 writes md[e].
__global__ __launch_bounds__(512) void kb_fill(
                        const int* __restrict__ ei, long E, const int* __restrict__ flags,
                        int NB, int NBp, int NC,
                        const int* __restrict__ hc, const int* __restrict__ bb,
                        const void* __restrict__ eu1, const void* __restrict__ eu2,
                        const void* __restrict__ eu3, const void* __restrict__ ed1,
                        const void* __restrict__ ed2, const void* __restrict__ ed3,
                        float* __restrict__ mu, float* __restrict__ md,
                        int2* __restrict__ bse_a, ushort_t* __restrict__ bse_w3) {
    extern __shared__ char dynlds[];
    int2* ssA      = (int2*)dynlds;               // CH*8  sorted (src|local<<24, w1|w2)
    ushort_t* ssW  = (ushort_t*)(ssA + CH);       // CH*2  w3
    ushort_t* sbkt = ssW + CH;                    // CH*2  bucket id
    int* h    = (int*)(sbkt + CH);                // NBp
    int* lofs = h + NBp;                          // NBp
    int* cur  = lofs + NBp;                       // NBp
    int* gb   = cur + NBp;                        // NBp
    int tid = threadIdx.x;
    int cidx = blockIdx.x;
    int dir = blockIdx.y;
    int is64 = flags[16];
    const void* w1p = dir ? ed1 : eu1;
    const void* w2p = dir ? ed2 : eu2;
    const void* w3p = dir ? ed3 : eu3;
    float* mout = dir ? md : mu;
    int f1 = flags[dir ? 5 : 4], f2 = flags[dir ? 10 : 9], f3 = flags[dir ? 15 : 14];
    for (int i = tid; i < NBp; i += 512) { h[i] = 0; cur[i] = 0; }
    // deterministic global base for this (chunk,dir): no atomics, no dependency
    for (int b = tid; b < NB; b += 512)
        gb[b] = bb[dir * (NBMAX + 1) + b] + hc[((long)dir * NC + cidx) * NB + b];
    __syncthreads();
    long base = (long)cidx * CH;
    const int EPT = CH / 512;   // 5
    int myd[EPT], mys[EPT], myw12[EPT];
    ushort_t myw3[EPT];
#pragma unroll
    for (int i = 0; i < EPT; i++) {
        long e = base + i * 512 + tid;
        myd[i] = -1;
        if (e < E) {
            myd[i] = lde(ei, dir ? 0 : 1, e, E, is64);
            mys[i] = lde(ei, dir ? 1 : 0, e, E, is64);
            float v1 = ldf(w1p, e, f1);
            float v2 = ldf(w2p, e, f2);
            float v3 = ldf(w3p, e, f3);
            myw12[i] = (unsigned)f2u(v1) | ((unsigned)f2u(v2) << 16);
            myw3[i] = f2u(v3);
            mout[e] = (v1 + v2 + v3) / 3.0f;
            atomicAdd(&h[myd[i] >> BSH], 1);
        }
    }
    __syncthreads();
    // single-wave exclusive scan of h[0..NBp) -> lofs
    if (tid < 64) {
        int carry = 0;
        for (int g = 0; g < NBp; g += 64) {
            int idx = g + tid;
            int v = (idx < NBp) ? h[idx] : 0;
            int x = v;
#pragma unroll
            for (int o = 1; o < 64; o <<= 1) {
                int y = __shfl_up(x, o, 64);
                if (tid >= o) x += y;
            }
            if (idx < NBp) lofs[idx] = x - v + carry;
            carry += __shfl(x, 63, 64);
        }
    }
    __syncthreads();
#pragma unroll
    for (int i = 0; i < EPT; i++) {
        if (myd[i] >= 0) {
            int b = myd[i] >> BSH;
            int r = atomicAdd(&cur[b], 1);
            int p = lofs[b] + r;
            ssA[p] = make_int2(mys[i] | ((myd[i] & 255) << 24), myw12[i]);
            ssW[p] = myw3[i];
            sbkt[p] = (ushort_t)b;
        }
    }
    __syncthreads();
    long rem = E - base;
    int nvalid = rem >= CH ? CH : (rem > 0 ? (int)rem : 0);
    int2* osA = bse_a + (long)dir * E;
    ushort_t* osW = bse_w3 + (long)dir * E;
    for (int s = tid; s < nvalid; s += 512) {
        int b = sbkt[s];
        long p = (long)gb[b] + (s - lofs[b]);
        osA[p] = ssA[s];
        osW[p] = ssW[s];
    }
}

// Per-(bucket,dir) counting sort into final per-node CSR. Sorted bucket staged
// in LDS (two half-passes over locals <128/>=128), then written out coalesced:
// list + the 3 CSR-ordered bf16 weight tables. No random global writes.
// 512 threads; single-wave shfl scan.
__global__ __launch_bounds__(512) void kb_csr(
                       const int* __restrict__ bb, const int2* __restrict__ bse_a,
                       const ushort_t* __restrict__ bse_w3,
                       long E, int NB, long N,
                       int* __restrict__ off_c, int* __restrict__ off_r,
                       int* __restrict__ list_c, int* __restrict__ list_r,
                       ushort_t* __restrict__ wc6) {
    __shared__ int2 sA[CSRCAP];         // 48 KB
    __shared__ ushort_t sW[CSRCAP];     // 12 KB
    __shared__ int h[256], lofs[256], cur[256];
    int tid = threadIdx.x;
    int b = blockIdx.x, dir = blockIdx.y;
    int base = bb[dir * (NBMAX + 1) + b];
    int cnt  = bb[dir * (NBMAX + 1) + b + 1] - base;
    const int2* bsA = bse_a + (long)dir * E;
    const ushort_t* bsW = bse_w3 + (long)dir * E;
    int* off  = dir ? off_r : off_c;
    int* list = dir ? list_r : list_c;
    ushort_t* o1 = wc6 + (long)(0 + dir) * E;   // layer1 (y = 2L+dir)
    ushort_t* o2 = wc6 + (long)(2 + dir) * E;   // layer2
    ushort_t* o3 = wc6 + (long)(4 + dir) * E;   // layer3
    if (tid < 256) { h[tid] = 0; cur[tid] = 0; }
    __syncthreads();
    int nb0 = b << BSH;
    for (int s = tid; s < cnt; s += 512)
        atomicAdd(&h[(unsigned)bsA[base + s].x >> 24], 1);
    __syncthreads();
    if (tid < 64) {
        int carry = 0;
#pragma unroll
        for (int g = 0; g < 4; g++) {
            int idx = g * 64 + tid;
            int v = h[idx];
            int x = v;
#pragma unroll
            for (int o = 1; o < 64; o <<= 1) {
                int y = __shfl_up(x, o, 64);
                if (tid >= o) x += y;
            }
            lofs[idx] = x - v + carry;
            carry += __shfl(x, 63, 64);
        }
    }
    __syncthreads();
    if (tid < 256) {
        long n = (long)nb0 + tid;
        if (n < N) off[n] = base + lofs[tid];
    }
    if (b == 0 && tid == 0) off[N] = (int)E;
    int mid = lofs[128];
    int cnt1 = cnt - mid;
    if (mid <= CSRCAP && cnt1 <= CSRCAP) {
        for (int s = tid; s < cnt; s += 512) {
            int2 se = bsA[base + s];
            int local = (unsigned)se.x >> 24;
            if (local < 128) {
                int r = atomicAdd(&cur[local], 1);
                int p = lofs[local] + r;
                sA[p] = se;
                sW[p] = bsW[base + s];
            }
        }
        __syncthreads();
        for (int s = tid; s < mid; s += 512) {
            int2 se = sA[s];
            list[base + s] = se.x & 0xFFFFFF;
            o1[base + s] = (ushort_t)((unsigned)se.y & 0xFFFF);
            o2[base + s] = (ushort_t)((unsigned)se.y >> 16);
            o3[base + s] = sW[s];
        }
        __syncthreads();
        for (int s = tid; s < cnt; s += 512) {
            int2 se = bsA[base + s];
            int local = (unsigned)se.x >> 24;
            if (local >= 128) {
                int r = atomicAdd(&cur[local], 1);
                int p = lofs[local] - mid + r;
                sA[p] = se;
                sW[p] = bsW[base + s];
            }
        }
        __syncthreads();
        for (int s = tid; s < cnt1; s += 512) {
            int2 se = sA[s];
            list[base + mid + s] = se.x & 0xFFFFFF;
            o1[base + mid + s] = (ushort_t)((unsigned)se.y & 0xFFFF);
            o2[base + mid + s] = (ushort_t)((unsigned)se.y >> 16);
            o3[base + mid + s] = sW[s];
        }
    } else {
        for (int s = tid; s < cnt; s += 512) {
            int2 se = bsA[base + s];
            int local = (unsigned)se.x >> 24;
            int r = atomicAdd(&cur[local], 1);
            long p = (long)base + lofs[local] + r;
            list[p] = se.x & 0xFFFFFF;
            o1[p] = (ushort_t)((unsigned)se.y & 0xFFFF);
            o2[p] = (ushort_t)((unsigned)se.y >> 16);
            o3[p] = bsW[base + s];
        }
    }
}

// ================================================================ phase-split gather (F==32)
// FOUR NODES PER WAVE (16 lanes each): 4 edge-subs x 4 feature-lanes per node;
// each lane loads uint4 (8 bf16 = 16B). Measured optimum of the node-packing
// family (r11: 2/wave 456.7, r13: +uint4 438.2, r14: 4/wave 424.1, r15:
// 8/wave 435.2 REGRESSED - longer per-node serial chains). One random table
// per dispatch -> per-XCD L2-resident (dual-table fusion thrashed L2).
__device__ __forceinline__ void gedge1(const int* __restrict__ list, const ushort_t* __restrict__ wc,
                                       const ushort_t* __restrict__ S, int j, int f8,
                                       float* a) {
    int s0 = list[j];
    float w0 = u2f(wc[j]);
    uint4 p0 = *(const uint4*)&S[((long)s0 << 5) + f8];
    a[0] += w0 * lo2f(p0.x); a[1] += w0 * hi2f(p0.x);
    a[2] += w0 * lo2f(p0.y); a[3] += w0 * hi2f(p0.y);
    a[4] += w0 * lo2f(p0.z); a[5] += w0 * hi2f(p0.z);
    a[6] += w0 * lo2f(p0.w); a[7] += w0 * hi2f(p0.w);
}
// 4 subs per node: sub in [0,4), len = ceil(deg/4).
__device__ __forceinline__ void gacc4(const int* __restrict__ list, const ushort_t* __restrict__ wc,
                                      const ushort_t* __restrict__ S, int j0, int j1, int sub, int f8,
                                      float* a) {
    int deg = j1 - j0;
    int len = (deg + 3) >> 2;
    int j = j0 + sub * len;
    int je = j + len; if (je > j1) je = j1;
    if (j < je && (j & 1)) { gedge1(list, wc, S, j, f8, a); j++; }
    for (; j + 3 < je; j += 4) {       // 4 edges, 4 random lines in flight
        int2 s01 = *(const int2*)&list[j];
        int2 s23 = *(const int2*)&list[j + 2];
        uint_t w01 = *(const uint_t*)&wc[j];
        uint_t w23 = *(const uint_t*)&wc[j + 2];
        uint4 p0 = *(const uint4*)&S[((long)s01.x << 5) + f8];
        uint4 p1 = *(const uint4*)&S[((long)s01.y << 5) + f8];
        uint4 p2 = *(const uint4*)&S[((long)s23.x << 5) + f8];
        uint4 p3 = *(const uint4*)&S[((long)s23.y << 5) + f8];
        float w0 = lo2f(w01), w1 = hi2f(w01), w2 = lo2f(w23), w3 = hi2f(w23);
        a[0] += w0 * lo2f(p0.x) + w1 * lo2f(p1.x) + w2 * lo2f(p2.x) + w3 * lo2f(p3.x);
        a[1] += w0 * hi2f(p0.x) + w1 * hi2f(p1.x) + w2 * hi2f(p2.x) + w3 * hi2f(p3.x);
        a[2] += w0 * lo2f(p0.y) + w1 * lo2f(p1.y) + w2 * lo2f(p2.y) + w3 * lo2f(p3.y);
        a[3] += w0 * hi2f(p0.y) + w1 * hi2f(p1.y) + w2 * hi2f(p2.y) + w3 * hi2f(p3.y);
        a[4] += w0 * lo2f(p0.z) + w1 * lo2f(p1.z) + w2 * lo2f(p2.z) + w3 * lo2f(p3.z);
        a[5] += w0 * hi2f(p0.z) + w1 * hi2f(p1.z) + w2 * hi2f(p2.z) + w3 * hi2f(p3.z);
        a[6] += w0 * lo2f(p0.w) + w1 * lo2f(p1.w) + w2 * lo2f(p2.w) + w3 * lo2f(p3.w);
        a[7] += w0 * hi2f(p0.w) + w1 * hi2f(p1.w) + w2 * hi2f(p2.w) + w3 * hi2f(p3.w);
    }
    if (j + 1 < je) {                  // 2 edges
        int2 s01 = *(const int2*)&list[j];
        uint_t w01 = *(const uint_t*)&wc[j];
        uint4 p0 = *(const uint4*)&S[((long)s01.x << 5) + f8];
        uint4 p1 = *(const uint4*)&S[((long)s01.y << 5) + f8];
        float w0 = lo2f(w01), w1 = hi2f(w01);
        a[0] += w0 * lo2f(p0.x) + w1 * lo2f(p1.x);
        a[1] += w0 * hi2f(p0.x) + w1 * hi2f(p1.x);
        a[2] += w0 * lo2f(p0.y) + w1 * lo2f(p1.y);
        a[3] += w0 * hi2f(p0.y) + w1 * hi2f(p1.y);
        a[4] += w0 * lo2f(p0.z) + w1 * lo2f(p1.z);
        a[5] += w0 * hi2f(p0.z) + w1 * hi2f(p1.z);
        a[6] += w0 * lo2f(p0.w) + w1 * lo2f(p1.w);
        a[7] += w0 * hi2f(p0.w) + w1 * hi2f(p1.w);
        j += 2;
    }
    if (j < je) gedge1(list, wc, S, j, f8, a);
}

// Phase A: up-direction (col-CSR over Su) -> U[n][32] fp32 (deg-normalized).
__global__ void k_gather_up(const int* __restrict__ off_c, const int* __restrict__ list_c,
                            const ushort_t* __restrict__ wcu, const ushort_t* __restrict__ Su,
                            long N, float* __restrict__ U) {
    long t = (long)blockIdx.x * blockDim.x + threadIdx.x;
    long quad = t >> 6;
    int lane = (int)(t & 63);
    long n = quad * 4 + (lane >> 4);
    if (n >= N) return;
    int hl = lane & 15;
    int sub = hl >> 2;       // 0..3
    int f8  = (hl & 3) << 3; // element offset 0,8,16,24
    int j0 = off_c[n], j1 = off_c[n + 1];
    float a[8] = {0.f, 0.f, 0.f, 0.f, 0.f, 0.f, 0.f, 0.f};
    gacc4(list_c, wcu, Su, j0, j1, sub, f8, a);
#pragma unroll
    for (int k = 0; k < 8; k++) {
        a[k] += __shfl_xor(a[k], 4, 16);
        a[k] += __shfl_xor(a[k], 8, 16);
    }
    if (sub == 0) {
        int deg = j1 - j0;
        float dinv = (deg > 0) ? 1.0f / (float)deg : 0.f;
        *(float4*)&U[(n << 5) + f8] =
            make_float4(a[0] * dinv, a[1] * dinv, a[2] * dinv, a[3] * dinv);
        *(float4*)&U[(n << 5) + f8 + 4] =
            make_float4(a[4] * dinv, a[5] * dinv, a[6] * dinv, a[7] * dinv);
    }
}

// Phase B: down-direction (row-CSR over Sd) + U + Sb -> normalize+leaky -> out.
__global__ void k_gather_downfin(const int* __restrict__ off_r, const int* __restrict__ list_r,
                                 const ushort_t* __restrict__ wcd, const ushort_t* __restrict__ Sd,
                                 const ushort_t* __restrict__ Sb, const float* __restrict__ U,
                                 long N, float* __restrict__ out) {
    long t = (long)blockIdx.x * blockDim.x + threadIdx.x;
    long quad = t >> 6;
    int lane = (int)(t & 63);
    long n = quad * 4 + (lane >> 4);
    if (n >= N) return;
    int hl = lane & 15;
    int sub = hl >> 2;
    int f8  = (hl & 3) << 3;
    int j0 = off_r[n], j1 = off_r[n + 1];
    float a[8] = {0.f, 0.f, 0.f, 0.f, 0.f, 0.f, 0.f, 0.f};
    gacc4(list_r, wcd, Sd, j0, j1, sub, f8, a);
#pragma unroll
    for (int k = 0; k < 8; k++) {
        a[k] += __shfl_xor(a[k], 4, 16);
        a[k] += __shfl_xor(a[k], 8, 16);
    }
    float v[8], u[8], c[8];
    float ss = 0.f;
    if (sub == 0) {
        int deg = j1 - j0;
        float dinv = (deg > 0) ? 1.0f / (float)deg : 0.f;
#pragma unroll
        for (int k = 0; k < 8; k++) { v[k] = a[k] * dinv; ss += v[k] * v[k]; }
        float4 uv0 = *(const float4*)&U[(n << 5) + f8];
        float4 uv1 = *(const float4*)&U[(n << 5) + f8 + 4];
        u[0] = uv0.x; u[1] = uv0.y; u[2] = uv0.z; u[3] = uv0.w;
        u[4] = uv1.x; u[5] = uv1.y; u[6] = uv1.z; u[7] = uv1.w;
#pragma unroll
        for (int k = 0; k < 8; k++) ss += u[k] * u[k];
        uint4 bp = *(const uint4*)&Sb[(n << 5) + f8];
        c[0] = lo2f(bp.x); c[1] = hi2f(bp.x); c[2] = lo2f(bp.y); c[3] = hi2f(bp.y);
        c[4] = lo2f(bp.z); c[5] = hi2f(bp.z); c[6] = lo2f(bp.w); c[7] = hi2f(bp.w);
#pragma unroll
        for (int k = 0; k < 8; k++) ss += c[k] * c[k];
    }
#pragma unroll
    for (int m = 1; m < 16; m <<= 1) ss += __shfl_xor(ss, m, 16);
    float inv = 1.0f / fmaxf(sqrtf(ss), 1e-12f);
    if (sub == 0) {
#pragma unroll
        for (int k = 0; k < 8; k++) { float x = u[k] * inv; u[k] = (x >= 0.f) ? x : 0.1f * x; }
#pragma unroll
        for (int k = 0; k < 8; k++) { float x = v[k] * inv; v[k] = (x >= 0.f) ? x : 0.1f * x; }
#pragma unroll
        for (int k = 0; k < 8; k++) { float x = c[k] * inv; c[k] = (x >= 0.f) ? x : 0.1f * x; }
        *(float4*)&out[n * 96 + f8]          = make_float4(u[0], u[1], u[2], u[3]);
        *(float4*)&out[n * 96 + f8 + 4]      = make_float4(u[4], u[5], u[6], u[7]);
        *(float4*)&out[n * 96 + 32 + f8]     = make_float4(v[0], v[1], v[2], v[3]);
        *(float4*)&out[n * 96 + 32 + f8 + 4] = make_float4(v[4], v[5], v[6], v[7]);
        *(float4*)&out[n * 96 + 64 + f8]     = make_float4(c[0], c[1], c[2], c[3]);
        *(float4*)&out[n * 96 + 64 + f8 + 4] = make_float4(c[4], c[5], c[6], c[7]);
    }
}

// ================================================================ specialized linear, din=96, dout=3x32 fused: MFMA
// mfma_f32_16x16x32_bf16, 64 nodes/block, 4 waves, 18 MFMA/wave. W staged in
// LDS pre-swizzled into B-fragment order; A rows bf16 padded to 104.
// C/D layout: col=lane&15, row=(lane>>4)*4+reg (HW-verified).
__global__ __launch_bounds__(256) void k_lin96(
                        const float* __restrict__ xin, long N,
                        const void* __restrict__ wu, const void* __restrict__ wd,
                        const void* __restrict__ wb, int wfi,
                        const int* __restrict__ flags,
                        ushort_t* __restrict__ Su, ushort_t* __restrict__ Sd,
                        ushort_t* __restrict__ Sb) {
    __shared__ ushort_t wlds[6 * 3 * 64 * 8];   // 18 KB: B-frags, [ntile][kstep][lane][8]
    __shared__ ushort_t alds[64 * 104];         // 13.3 KB: A rows bf16, stride 104
    int tid = threadIdx.x;
    int ubf = flags[wfi], dbf = flags[wfi + 1], bbf = flags[wfi + 2];
    // stage W: slot (t,s,l) holds W[k = s*32 + (l>>4)*8 + j][n = t*16 + (l&15)]
    for (int idx = tid; idx < 6 * 3 * 64; idx += 256) {
        int t = idx / (3 * 64);
        int rem = idx - t * 3 * 64;
        int s = rem >> 6;
        int l = rem & 63;
        int n = t * 16 + (l & 15);
        int kg = l >> 4;
        const void* w = (n < 32) ? wu : (n < 64) ? wd : wb;
        int f = (n < 32) ? ubf : (n < 64) ? dbf : bbf;
        int o = n & 31;
        ushort_t tmp[8];
#pragma unroll
        for (int j = 0; j < 8; j++)
            tmp[j] = f2u(ldf(w, (long)o * 96 + s * 32 + kg * 8 + j, f));
        *(bf16x8*)&wlds[idx * 8] = *(const bf16x8*)tmp;
    }
    long nb = (long)blockIdx.x * 64;
    for (int j = tid; j < 64 * 24; j += 256) {   // 1536 float4, coalesced
        int node = j / 24, c = j % 24;
        long gn = nb + node;
        float4 v = make_float4(0.f, 0.f, 0.f, 0.f);
        if (gn < N) v = ((const float4*)(xin + gn * 96))[c];
        ushort_t* dst = &alds[node * 104 + c * 4];
        dst[0] = f2u(v.x); dst[1] = f2u(v.y); dst[2] = f2u(v.z); dst[3] = f2u(v.w);
    }
    __syncthreads();
    int wv = tid >> 6;          // wave 0..3 -> rows wv*16..wv*16+15
    int lane = tid & 63;
    int m0 = lane & 15;
    int kg = lane >> 4;
    int row = wv * 16 + m0;
    f32x4 acc[6];
#pragma unroll
    for (int t = 0; t < 6; t++) acc[t] = (f32x4){0.f, 0.f, 0.f, 0.f};
#pragma unroll
    for (int s = 0; s < 3; s++) {
        bf16x8 a = *(const bf16x8*)&alds[row * 104 + s * 32 + kg * 8];
#pragma unroll
        for (int t = 0; t < 6; t++) {
            bf16x8 b = *(const bf16x8*)&wlds[((t * 3 + s) * 64 + lane) * 8];
            acc[t] = __builtin_amdgcn_mfma_f32_16x16x32_bf16(a, b, acc[t], 0, 0, 0);
        }
    }
    __syncthreads();                       // all A reads done; reuse alds as C staging
    ushort_t* sbuf = alds;                 // 64*96 = 6144 ushorts < 64*104
#pragma unroll
    for (int t = 0; t < 6; t++) {
        int n = t * 16 + (lane & 15);
#pragma unroll
        for (int r = 0; r < 4; r++) {
            int m = (lane >> 4) * 4 + r;
            sbuf[(wv * 16 + m) * 96 + n] = f2u(acc[t][r]);
        }
    }
    __syncthreads();
    for (int j = tid; j < 64 * 96; j += 256) {
        int nd = j / 96, o3 = j % 96;
        long gn = nb + nd;
        if (gn < N) {
            int blk = o3 >> 5, fo = o3 & 31;
            ushort_t v = sbuf[j];
            (blk == 0 ? Su : blk == 1 ? Sd : Sb)[gn * 32 + fo] = v;
        }
    }
}

// ================================================================ generic linear -> bf16 S arrays (layer 1)
__global__ void k_linear_b16(const void* __restrict__ xin, int xfi, int din, int dout, long N,
                             const void* __restrict__ wu, const void* __restrict__ wd,
                             const void* __restrict__ wb, int wfi,
                             const int* __restrict__ flags, int uselds,
                             ushort_t* __restrict__ Su, ushort_t* __restrict__ Sd,
                             ushort_t* __restrict__ Sb) {
    __shared__ float smem[12288];
    int xbf = (xfi >= 0) ? flags[xfi] : 0;
    int ubf = flags[wfi], dbf = flags[wfi + 1], bbf = flags[wfi + 2];
    float* su = smem;
    float* sd = smem + (long)din * dout;
    float* sb = smem + 2l * din * dout;
    if (uselds) {
        for (int j = threadIdx.x; j < din * dout; j += 256) {
            int o = j % dout, i = j / dout;
            su[j] = ldf(wu, (long)o * din + i, ubf);
            sd[j] = ldf(wd, (long)o * din + i, dbf);
            sb[j] = ldf(wb, (long)o * din + i, bbf);
        }
        __syncthreads();
    }
    long idx = (long)blockIdx.x * blockDim.x + threadIdx.x;
    long node = idx / dout;
    int o = (int)(idx % dout);
    if (node >= N) return;
    float au = 0.f, ad = 0.f, ab = 0.f;
    long xb = node * din;
    if (uselds) {
        for (int i = 0; i < din; i++) {
            float xv = ldf(xin, xb + i, xbf);
            au += xv * su[i * dout + o];
            ad += xv * sd[i * dout + o];
            ab += xv * sb[i * dout + o];
        }
    } else {
        for (int i = 0; i < din; i++) {
            float xv = ldf(xin, xb + i, xbf);
            au += xv * ldf(wu, (long)o * din + i, ubf);
            ad += xv * ldf(wd, (long)o * din + i, dbf);
            ab += xv * ldf(wb, (long)o * din + i, bbf);
        }
    }
    Su[node * dout + o] = f2u(au);
    Sd[node * dout + o] = f2u(ad);
    Sb[node * dout + o] = f2u(ab);
}

// ================================================================ fallback (round-4 proven) kernels
__global__ void k_linear(const void* __restrict__ xin, int xfi, int din, int dout, int rs, long N,
                         const void* __restrict__ wu, const void* __restrict__ wd,
                         const void* __restrict__ wb, int wfi,
                         const int* __restrict__ flags, int uselds,
                         float* __restrict__ A, float* __restrict__ B, float* __restrict__ C) {
    __shared__ float smem[12288];
    int xbf = (xfi >= 0) ? flags[xfi] : 0;
    int ubf = flags[wfi], dbf = flags[wfi + 1], bbf = flags[wfi + 2];
    float* su = smem;
    float* sd = smem + (long)din * dout;
    float* sb = smem + 2l * din * dout;
    if (uselds) {
        for (int j = threadIdx.x; j < din * dout; j += 256) {
            int o = j % dout, i = j / dout;
            su[j] = ldf(wu, (long)o * din + i, ubf);
            sd[j] = ldf(wd, (long)o * din + i, dbf);
            sb[j] = ldf(wb, (long)o * din + i, bbf);
        }
        __syncthreads();
    }
    long idx = (long)blockIdx.x * blockDim.x + threadIdx.x;
    long node = idx / dout;
    int o = (int)(idx % dout);
    if (node >= N) return;
    float au = 0.f, ad = 0.f, ab = 0.f;
    long xb = node * din;
    if (uselds) {
        for (int i = 0; i < din; i++) {
            float xv = ldf(xin, xb + i, xbf);
            au += xv * su[i * dout + o];
            ad += xv * sd[i * dout + o];
            ab += xv * sb[i * dout + o];
        }
    } else {
        for (int i = 0; i < din; i++) {
            float xv = ldf(xin, xb + i, xbf);
            au += xv * ldf(wu, (long)o * din + i, ubf);
            ad += xv * ldf(wd, (long)o * din + i, dbf);
            ab += xv * ldf(wb, (long)o * din + i, bbf);
        }
    }
    A[node * rs + o] = au;
    B[node * rs + o] = ad;
    C[node * rs + o] = ab;
}

__global__ void k_deg(const int* __restrict__ ei, long E, const int* __restrict__ flags,
                      float* __restrict__ degc, float* __restrict__ degr) {
    long e = (long)blockIdx.x * blockDim.x + threadIdx.x;
    if (e < E) {
        int is64 = flags[16];
        atomicAdd(&degc[lde(ei, 1, e, E, is64)], 1.0f);
        atomicAdd(&degr[lde(ei, 0, e, E, is64)], 1.0f);
    }
}

__global__ void k_inv(float* __restrict__ a, long n) {
    long i = (long)blockIdx.x * blockDim.x + threadIdx.x;
    if (i < n) { float v = a[i]; a[i] = (v > 0.0f) ? 1.0f / v : 0.0f; }
}

__global__ void k_scatter(const int* __restrict__ ei, long E, int F,
                          const void* __restrict__ ewu, const void* __restrict__ ewd,
                          int fu, int fd, const int* __restrict__ flags,
                          const float* __restrict__ degci, const float* __restrict__ degri,
                          const float* __restrict__ A, const float* __restrict__ B,
                          float* __restrict__ U, float* __restrict__ D) {
    long idx = (long)blockIdx.x * blockDim.x + threadIdx.x;
    long tot = E * 2 * F;
    if (idx >= tot) return;
    int is64 = flags[16];
    long e = idx / (2 * F);
    int rem = (int)(idx - e * 2 * F);
    int dir = rem >= F;
    int f = rem - dir * F;
    int r = lde(ei, 0, e, E, is64), c = lde(ei, 1, e, E, is64);
    if (!dir) {
        float w = degci[c] * ldf(ewu, e, flags[fu]);
        atomicAdd(&U[(long)c * F + f], w * A[(long)r * F + f]);
    } else {
        float w = degri[r] * ldf(ewd, e, flags[fd]);
        atomicAdd(&D[(long)r * F + f], w * B[(long)c * F + f]);
    }
}

__global__ void k_finalize(const float* __restrict__ U, const float* __restrict__ D,
                           const float* __restrict__ C, int F, long N,
                           float* __restrict__ out) {
    long t = (long)blockIdx.x * blockDim.x + threadIdx.x;
    long n = t >> 6;
    if (n >= N) return;
    int lane = (int)(t & 63);
    int cat = 3 * F;
    float ss = 0.f;
    for (int j = lane; j < cat; j += 64) {
        float v = (j < F) ? U[n * F + j] : (j < 2 * F) ? D[n * F + j - F] : C[n * F + j - 2 * F];
        ss += v * v;
    }
#pragma unroll
    for (int m = 1; m < 64; m <<= 1) ss += __shfl_xor(ss, m, 64);
    float inv = 1.0f / fmaxf(sqrtf(ss), 1e-12f);
    for (int j = lane; j < cat; j += 64) {
        float v = (j < F) ? U[n * F + j] : (j < 2 * F) ? D[n * F + j - F] : C[n * F + j - 2 * F];
        float a = v * inv;
        a = (a >= 0.0f) ? a : 0.1f * a;
        out[n * cat + j] = a;
    }
}

__global__ void k_mean(const void* e1u, const void* e2u, const void* e3u,
                       const void* e1d, const void* e2d, const void* e3d,
                       const int* __restrict__ flags, long E,
                       float* __restrict__ mu, float* __restrict__ md) {
    long e = (long)blockIdx.x * blockDim.x + threadIdx.x;
    if (e >= E) return;
    float su = ldf(e1u, e, flags[4]) + ldf(e2u, e, flags[9]) + ldf(e3u, e, flags[14]);
    float sd = ldf(e1d, e, flags[5]) + ldf(e2d, e, flags[10]) + ldf(e3d, e, flags[15]);
    mu[e] = su / 3.0f;
    md[e] = sd / 3.0f;
}

extern "C" void kernel_launch(void* const* d_in, const int* in_sizes, int n_in,
                              void* d_out, int out_size, void* d_ws, size_t ws_size,
                              hipStream_t stream) {
    const int* ei = (const int*)d_in[1];
    const void* w_up[3]   = {d_in[2], d_in[7],  d_in[12]};
    const void* w_down[3] = {d_in[3], d_in[8],  d_in[13]};
    const void* w_bias[3] = {d_in[4], d_in[9],  d_in[14]};
    const void* ew_up[3]  = {d_in[5], d_in[10], d_in[15]};
    const void* ew_down[3]= {d_in[6], d_in[11], d_in[16]};

    // ---- derive true sizes from in_sizes
    long E = in_sizes[5];
    if (E <= 0) E = 1600000;
    int HID = (int)(sqrt((double)in_sizes[7] / 3.0) + 0.5);
    if (HID <= 0 || (long)3 * HID * HID != (long)in_sizes[7]) HID = 32;
    int DIN = in_sizes[2] / HID;
    if (DIN <= 0) DIN = 8;
    long N = (long)in_sizes[0] / DIN;
    if (N <= 0) N = 50000;
    int EMB = in_sizes[12] / (3 * HID);
    if (EMB <= 0) EMB = 32;
    int Fm = HID > EMB ? HID : EMB;
    int NB = (int)((N + 255) >> BSH);
    int NBp = (NB + 1) & ~1;
    int NC = (int)((E + CH - 1) / CH);

    // ---- outputs: fp32, concatenated (h, mean_up, mean_down)
    float* out_h  = (float*)d_out;
    float* out_mu = out_h + N * 3l * EMB;
    float* out_md = out_mu + E;

    const int TB = 256;
    int lds1  = (3l * DIN * HID <= 12288) ? 1 : 0;
    int lds12 = (3l * (3 * HID) * HID <= 12288) ? 1 : 0;
    int lds3  = (3l * (3 * HID) * EMB <= 12288) ? 1 : 0;
    dim3 linG1((unsigned)((N * HID + TB - 1) / TB));
    dim3 linG3((unsigned)((N * EMB + TB - 1) / TB));
    dim3 lin96G((unsigned)((N + 63) / 64));
    dim3 finG((unsigned)((N * 64 + TB - 1) / TB));
    long nquad = (N + 3) / 4;
    dim3 finG4((unsigned)((nquad * 64 + TB - 1) / TB));
    dim3 edgeG((unsigned)((E + TB - 1) / TB));
    dim3 chunkG1((unsigned)NC);
    dim3 chunkG2((unsigned)NC, 2);
    size_t fillLds = (size_t)CH * 12 + (size_t)(4 * NBp) * 4;

    // ---- fast-path workspace layout
    int* flags = (int*)d_ws;                       // 64
    int* bc    = flags + 64;                       // 2*NBMAX
    int* bb    = bc + 2 * NBMAX;                   // 2*(NBMAX+1)
    int* off_c = bb + 2 * (NBMAX + 1);             // N+1
    int* off_r = off_c + (N + 1);                  // N+1
    int* hc    = off_r + (N + 1);                  // 2*NC*NB per-chunk hist/prefix
    long li = (long)(hc + 2l * NC * NB - (int*)d_ws);
    li = (li + 3) & ~3l;
    int* list_c = (int*)d_ws + li;                 // E (src only - gather hot path)
    int* list_r = list_c + E;                      // E
    ushort_t* wc6 = (ushort_t*)(list_r + E);       // 6E ushorts = 3E ints (CSR weights)
    int* X = list_r + E + 3 * E;                   // overlay region
    // phase 1 (bucket build): bse_a 2E int2 = 4E ints, bse_w3 2E ushorts = E ints
    int2* bse_a = (int2*)X;
    ushort_t* bse_w3 = (ushort_t*)(X + 4 * E);
    // phase 2+: S/U arrays overlay X (bse dead after kb_csr)
    ushort_t* Su = (ushort_t*)X;                   // N*Fm
    ushort_t* Sd = Su + N * Fm;
    ushort_t* Sb = Sd + N * Fm;
    float* U = (float*)(Sb + N * Fm);              // N*Fm fp32 (int-aligned: 3*N*Fm even)
    long zInts = (3l * N * Fm + 1) / 2 + N * Fm;   // S arrays + U
    long Xints = 5l * E;                           // phase 1 (bse_a + bse_w3)
    if (zInts > Xints) Xints = zInts;
    size_t need = (size_t)((li + 5l * E + Xints) * 4l + 256);

    bool fast = (HID == 32 && EMB == 32) && (NB <= NBMAX) && (NC <= NCMAX) &&
                (ws_size == 0 || ws_size >= need);

    // ---- dtype detection (both paths)
    DetectArgs da;
    da.p[0] = d_in[0]; da.n[0] = in_sizes[0];
    for (int L = 0; L < 3; L++) {
        da.p[1 + 5 * L] = w_up[L];    da.n[1 + 5 * L] = in_sizes[2 + 5 * L];
        da.p[2 + 5 * L] = w_down[L];  da.n[2 + 5 * L] = in_sizes[3 + 5 * L];
        da.p[3 + 5 * L] = w_bias[L];  da.n[3 + 5 * L] = in_sizes[4 + 5 * L];
        da.p[4 + 5 * L] = ew_up[L];   da.n[4 + 5 * L] = in_sizes[5 + 5 * L];
        da.p[5 + 5 * L] = ew_down[L]; da.n[5 + 5 * L] = in_sizes[6 + 5 * L];
    }
    da.ei = ei; da.E = E; da.flags = flags;
    k_detect<<<17, TB, 0, stream>>>(da);

    if (fast) {
        // ---- bucketed CSR build, deterministic bases (no global atomics);
        //      kb_fill also writes the mean outputs (fused, one pass)
        kb_count<<<chunkG1, TB, 0, stream>>>(ei, E, flags, NB, NC, hc);
        kb_scanA<<<dim3((unsigned)NB, 2), 256, 0, stream>>>(hc, NC, NB, bc);
        kb_scanB<<<1, 64, 0, stream>>>(bc, bb, NB);
        kb_fill<<<chunkG2, 512, fillLds, stream>>>(ei, E, flags, NB, NBp, NC, hc, bb,
                                                   ew_up[0], ew_up[1], ew_up[2],
                                                   ew_down[0], ew_down[1], ew_down[2],
                                                   out_mu, out_md,
                                                   bse_a, bse_w3);
        kb_csr<<<dim3((unsigned)NB, 2), 512, 0, stream>>>(bb, bse_a, bse_w3, E, NB, N,
                                                          off_c, off_r, list_c, list_r,
                                                          wc6);

        float* H = (float*)d_out;   // intermediate 96-wide activations live in d_out

        // ---- layer 1 (din=DIN, generic, bf16 S output)
        k_linear_b16<<<linG1, TB, 0, stream>>>(d_in[0], 0, DIN, HID, N,
                                               w_up[0], w_down[0], w_bias[0], 1, flags, lds1,
                                               Su, Sd, Sb);
        k_gather_up<<<finG4, TB, 0, stream>>>(off_c, list_c, wc6, Su, N, U);
        k_gather_downfin<<<finG4, TB, 0, stream>>>(off_r, list_r, wc6 + E, Sd, Sb, U, N, H);
        // ---- layer 2 (din=96 MFMA)
        k_lin96<<<lin96G, 256, 0, stream>>>(H, N, w_up[1], w_down[1], w_bias[1], 6, flags,
                                            Su, Sd, Sb);
        k_gather_up<<<finG4, TB, 0, stream>>>(off_c, list_c, wc6 + 2l * E, Su, N, U);
        k_gather_downfin<<<finG4, TB, 0, stream>>>(off_r, list_r, wc6 + 3l * E, Sd, Sb, U, N, H);
        // ---- layer 3 -> final fp32 output
        k_lin96<<<lin96G, 256, 0, stream>>>(H, N, w_up[2], w_down[2], w_bias[2], 11, flags,
                                            Su, Sd, Sb);
        k_gather_up<<<finG4, TB, 0, stream>>>(off_c, list_c, wc6 + 4l * E, Su, N, U);
        k_gather_downfin<<<finG4, TB, 0, stream>>>(off_r, list_r, wc6 + 5l * E, Sd, Sb, U, N, out_h);
    } else {
        // ---- fallback: round-4 proven atomic-scatter path
        float* degci = (float*)(flags + 64);
        float* degri = degci + N;
        float* fA = degri + N;
        float* fB = fA + N * Fm;
        float* fC = fB + N * Fm;
        float* fU = fC + N * Fm;
        float* fD = fU + N * Fm;
        float* fH = fD + N * Fm;
        dim3 scatG12((unsigned)((E * 2 * HID + TB - 1) / TB));
        dim3 scatG3((unsigned)((E * 2 * EMB + TB - 1) / TB));

        hipMemsetAsync(degci, 0, 2 * N * sizeof(float), stream);
        k_deg<<<edgeG, TB, 0, stream>>>(ei, E, flags, degci, degri);
        k_inv<<<dim3((unsigned)((2 * N + TB - 1) / TB)), TB, 0, stream>>>(degci, 2 * N);

        k_linear<<<linG1, TB, 0, stream>>>(d_in[0], 0, DIN, HID, HID, N,
                                           w_up[0], w_down[0], w_bias[0], 1, flags, lds1, fA, fB, fC);
        hipMemsetAsync(fU, 0, 2l * N * Fm * sizeof(float), stream);
        k_scatter<<<scatG12, TB, 0, stream>>>(ei, E, HID, ew_up[0], ew_down[0], 4, 5, flags,
                                              degci, degri, fA, fB, fU, fD);
        k_finalize<<<finG, TB, 0, stream>>>(fU, fD, fC, HID, N, fH);

        k_linear<<<linG1, TB, 0, stream>>>(fH, -1, 3 * HID, HID, HID, N,
                                           w_up[1], w_down[1], w_bias[1], 6, flags, lds12, fA, fB, fC);
        hipMemsetAsync(fU, 0, 2l * N * Fm * sizeof(float), stream);
        k_scatter<<<scatG12, TB, 0, stream>>>(ei, E, HID, ew_up[1], ew_down[1], 9, 10, flags,
                                              degci, degri, fA, fB, fU, fD);
        k_finalize<<<finG, TB, 0, stream>>>(fU, fD, fC, HID, N, fH);

        k_linear<<<linG3, TB, 0, stream>>>(fH, -1, 3 * HID, EMB, EMB, N,
                                           w_up[2], w_down[2], w_bias[2], 11, flags, lds3, fA, fB, fC);
        hipMemsetAsync(fU, 0, 2l * N * Fm * sizeof(float), stream);
        k_scatter<<<scatG3, TB, 0, stream>>>(ei, E, EMB, ew_up[2], ew_down[2], 14, 15, flags,
                                             degci, degri, fA, fB, fU, fD);
        k_finalize<<<finG, TB, 0, stream>>>(fU, fD, fC, EMB, N, out_h);

        k_mean<<<edgeG, TB, 0, stream>>>(ew_up[0], ew_up[1], ew_up[2],
                                         ew_down[0], ew_down[1], ew_down[2],
                                         flags, E, out_mu, out_md);
    }
}